// Round 1
// baseline (987.457 us; speedup 1.0000x reference)
//
#include <hip/hip_runtime.h>

typedef __bf16 bf16x8 __attribute__((ext_vector_type(8)));
typedef float f32x4 __attribute__((ext_vector_type(4)));

__device__ __forceinline__ unsigned short f2bf(float x) {
  union { float f; unsigned int u; } c; c.f = x;
  unsigned int r = c.u + 0x7FFFu + ((c.u >> 16) & 1u);
  return (unsigned short)(r >> 16);
}

// ---------------- convert f32 -> bf16 (vectorized) ----------------
__global__ __launch_bounds__(256) void f32_to_bf16_vec4(
    const float* __restrict__ in, unsigned short* __restrict__ out, int n4) {
  int i = blockIdx.x * blockDim.x + threadIdx.x;
  int stride = gridDim.x * blockDim.x;
  const float4* in4 = (const float4*)in;
  ushort4* out4 = (ushort4*)out;
  for (; i < n4; i += stride) {
    float4 f = in4[i];
    ushort4 u;
    u.x = f2bf(f.x); u.y = f2bf(f.y); u.z = f2bf(f.z); u.w = f2bf(f.w);
    out4[i] = u;
  }
}

// ---------------- GEMM: C[m][n] = sum_k A[m][k]*B[n][k] + bias[n] ----------------
// A: MxK bf16 row-major, B: NxK bf16 row-major ("B^T" GEMM). 128x128 tile, BK=64,
// 256 threads (4 waves, 2x2), global_load_lds width 16, m97 2-barrier structure.
#define GLOAD_LDS16(gp, lp)                                                          \
  __builtin_amdgcn_global_load_lds(                                                  \
      (const __attribute__((address_space(1))) unsigned int*)(uintptr_t)(gp),        \
      (__attribute__((address_space(3))) unsigned int*)(uintptr_t)(lp), 16, 0, 0)

template <bool BF16OUT>
__global__ __launch_bounds__(256) void gemm_bt(
    const unsigned short* __restrict__ A,
    const unsigned short* __restrict__ B,
    const float* __restrict__ bias,
    void* __restrict__ Cv,
    int K, int ldc) {
  __shared__ unsigned short As[128 * 64];
  __shared__ unsigned short Bs[128 * 64];
  const int t = threadIdx.x;
  const int lane = t & 63;
  const int wid = t >> 6;
  const int wr = wid >> 1, wc = wid & 1;
  const int lr = lane & 15, lg = lane >> 4;
  const int m0 = blockIdx.y * 128;
  const int n0 = blockIdx.x * 128;

  const int srow = t >> 3;          // 0..31
  const int scol = (t & 7) * 8;     // 0..56
  const unsigned short* ga0 = A + (size_t)(m0 + srow) * K + scol;
  const unsigned short* gb0 = B + (size_t)(n0 + srow) * K + scol;
  unsigned short* la = As + t * 8;
  unsigned short* lb = Bs + t * 8;

  f32x4 acc[4][4];
#pragma unroll
  for (int i = 0; i < 4; ++i)
#pragma unroll
    for (int j = 0; j < 4; ++j) acc[i][j] = f32x4{0.f, 0.f, 0.f, 0.f};

  const int nkb = K >> 6;
  for (int kb = 0; kb < nkb; ++kb) {
    __syncthreads();  // previous compute done reading LDS
    const unsigned short* ga = ga0 + kb * 64;
    const unsigned short* gb = gb0 + kb * 64;
#pragma unroll
    for (int i = 0; i < 4; ++i) {
      GLOAD_LDS16(ga + (size_t)(32 * i) * K, la + i * 2048);
      GLOAD_LDS16(gb + (size_t)(32 * i) * K, lb + i * 2048);
    }
    __syncthreads();  // vmcnt(0) drain: staged tile visible
#pragma unroll
    for (int ki = 0; ki < 2; ++ki) {
      bf16x8 af[4], bfr[4];
#pragma unroll
      for (int mt = 0; mt < 4; ++mt)
        af[mt] = *(const bf16x8*)(As + (wr * 64 + mt * 16 + lr) * 64 + ki * 32 + lg * 8);
#pragma unroll
      for (int nt = 0; nt < 4; ++nt)
        bfr[nt] = *(const bf16x8*)(Bs + (wc * 64 + nt * 16 + lr) * 64 + ki * 32 + lg * 8);
#pragma unroll
      for (int mt = 0; mt < 4; ++mt)
#pragma unroll
        for (int nt = 0; nt < 4; ++nt)
          acc[mt][nt] = __builtin_amdgcn_mfma_f32_16x16x32_bf16(af[mt], bfr[nt], acc[mt][nt], 0, 0, 0);
    }
  }

#pragma unroll
  for (int mt = 0; mt < 4; ++mt) {
#pragma unroll
    for (int nt = 0; nt < 4; ++nt) {
      const int n = n0 + wc * 64 + nt * 16 + lr;
      const float bv = bias[n];
#pragma unroll
      for (int r = 0; r < 4; ++r) {
        const int m = m0 + wr * 64 + mt * 16 + lg * 4 + r;
        const float v = acc[mt][nt][r] + bv;
        if constexpr (BF16OUT)
          ((unsigned short*)Cv)[(size_t)m * ldc + n] = f2bf(v);
        else
          ((float*)Cv)[(size_t)m * ldc + n] = v;
      }
    }
  }
}

// ---------------- fused window attention: one wave per (window b, head h) ----------------
// qkv: [B*64][1536] bf16 (q: 0..512, k: 512..1024, v: 1024..1536; head h at h*32)
__global__ __launch_bounds__(64) void attn_kernel(
    const unsigned short* __restrict__ qkv,
    const float* __restrict__ bias_table,  // [127][16]
    const float* __restrict__ mask,        // [64][64][64]
    unsigned short* __restrict__ attn_out  // [B*64][512] bf16, col = h*32+d
) {
  const int bh = blockIdx.x;
  const int b = bh >> 4;
  const int h = bh & 15;
  const int lane = threadIdx.x;
  const int lr = lane & 15, lg = lane >> 4;

  __shared__ unsigned short Vt[32 * 72];  // V^T: [d][key], stride 72 (144B, 16B-aligned)
  __shared__ unsigned short Pl[64 * 72];  // P:   [q][key]

  const unsigned short* base = qkv + (size_t)b * 64 * 1536;

  // V row per lane (32 bf16), later transposed into LDS
  const unsigned short* vp = base + (size_t)lane * 1536 + 1024 + h * 32;
  bf16x8 vr0 = ((const bf16x8*)vp)[0];
  bf16x8 vr1 = ((const bf16x8*)vp)[1];
  bf16x8 vr2 = ((const bf16x8*)vp)[2];
  bf16x8 vr3 = ((const bf16x8*)vp)[3];

  // Q (A-frag) / K (B-frag): lane holds row (l&15), k-chunk 8*(l>>4)
  bf16x8 qf[4], kf[4];
#pragma unroll
  for (int mt = 0; mt < 4; ++mt)
    qf[mt] = *(const bf16x8*)(base + (size_t)(mt * 16 + lr) * 1536 + h * 32 + lg * 8);
#pragma unroll
  for (int nt = 0; nt < 4; ++nt)
    kf[nt] = *(const bf16x8*)(base + (size_t)(nt * 16 + lr) * 1536 + 512 + h * 32 + lg * 8);

  f32x4 s[4][4];
#pragma unroll
  for (int i = 0; i < 4; ++i)
#pragma unroll
    for (int j = 0; j < 4; ++j) s[i][j] = f32x4{0.f, 0.f, 0.f, 0.f};
#pragma unroll
  for (int mt = 0; mt < 4; ++mt)
#pragma unroll
    for (int nt = 0; nt < 4; ++nt)
      s[mt][nt] = __builtin_amdgcn_mfma_f32_16x16x32_bf16(qf[mt], kf[nt], s[mt][nt], 0, 0, 0);

  // transpose V into LDS
  {
    __bf16* vt = (__bf16*)Vt;
#pragma unroll
    for (int d = 0; d < 8; ++d) {
      vt[(d)*72 + lane] = vr0[d];
      vt[(d + 8) * 72 + lane] = vr1[d];
      vt[(d + 16) * 72 + lane] = vr2[d];
      vt[(d + 24) * 72 + lane] = vr3[d];
    }
  }

  const float scale = 0.17677669529663687f;  // 32^-0.5
  const float* mrow = mask + (size_t)(b & 63) * 4096;
  float rsum[4][4];
#pragma unroll
  for (int mt = 0; mt < 4; ++mt) {
#pragma unroll
    for (int r = 0; r < 4; ++r) {
      const int m = mt * 16 + lg * 4 + r;
      float v[4];
#pragma unroll
      for (int nt = 0; nt < 4; ++nt) {
        const int n = nt * 16 + lr;
        v[nt] = s[mt][nt][r] * scale + bias_table[(m - n + 63) * 16 + h] + mrow[m * 64 + n];
      }
      float mx = fmaxf(fmaxf(v[0], v[1]), fmaxf(v[2], v[3]));
      mx = fmaxf(mx, __shfl_xor(mx, 1, 64));
      mx = fmaxf(mx, __shfl_xor(mx, 2, 64));
      mx = fmaxf(mx, __shfl_xor(mx, 4, 64));
      mx = fmaxf(mx, __shfl_xor(mx, 8, 64));
      float sum = 0.f;
#pragma unroll
      for (int nt = 0; nt < 4; ++nt) {
        v[nt] = __expf(v[nt] - mx);
        sum += v[nt];
      }
      sum += __shfl_xor(sum, 1, 64);
      sum += __shfl_xor(sum, 2, 64);
      sum += __shfl_xor(sum, 4, 64);
      sum += __shfl_xor(sum, 8, 64);
      rsum[mt][r] = sum;
#pragma unroll
      for (int nt = 0; nt < 4; ++nt)
        Pl[m * 72 + nt * 16 + lr] = f2bf(v[nt]);
    }
  }

  __syncthreads();  // LDS writes (Vt, Pl) visible to reads below

  f32x4 o[4][2];
#pragma unroll
  for (int i = 0; i < 4; ++i)
#pragma unroll
    for (int j = 0; j < 2; ++j) o[i][j] = f32x4{0.f, 0.f, 0.f, 0.f};
#pragma unroll
  for (int ki = 0; ki < 2; ++ki) {
    bf16x8 pa[4], vb[2];
#pragma unroll
    for (int mt = 0; mt < 4; ++mt)
      pa[mt] = *(const bf16x8*)(Pl + (mt * 16 + lr) * 72 + ki * 32 + lg * 8);
#pragma unroll
    for (int dt = 0; dt < 2; ++dt)
      vb[dt] = *(const bf16x8*)(Vt + (dt * 16 + lr) * 72 + ki * 32 + lg * 8);
#pragma unroll
    for (int mt = 0; mt < 4; ++mt)
#pragma unroll
      for (int dt = 0; dt < 2; ++dt)
        o[mt][dt] = __builtin_amdgcn_mfma_f32_16x16x32_bf16(pa[mt], vb[dt], o[mt][dt], 0, 0, 0);
  }

#pragma unroll
  for (int mt = 0; mt < 4; ++mt) {
#pragma unroll
    for (int r = 0; r < 4; ++r) {
      const float rinv = 1.0f / rsum[mt][r];
      const int m = mt * 16 + lg * 4 + r;
#pragma unroll
      for (int dt = 0; dt < 2; ++dt) {
        const int d = dt * 16 + lr;
        attn_out[(size_t)(b * 64 + m) * 512 + h * 32 + d] = f2bf(o[mt][dt][r] * rinv);
      }
    }
  }
}

// ---------------- launch ----------------
extern "C" void kernel_launch(void* const* d_in, const int* in_sizes, int n_in,
                              void* d_out, int out_size, void* d_ws, size_t ws_size,
                              hipStream_t stream) {
  const float* X = (const float*)d_in[0];
  const float* mask = (const float*)d_in[1];
  const float* qkv_w = (const float*)d_in[2];
  const float* qkv_b = (const float*)d_in[3];
  const float* proj_w = (const float*)d_in[4];
  const float* proj_b = (const float*)d_in[5];
  const float* bias_table = (const float*)d_in[6];
  float* out = (float*)d_out;
  char* ws = (char*)d_ws;

  // workspace layout (bytes)
  unsigned short* Xb      = (unsigned short*)(ws);                 // 134,217,728
  unsigned short* qkvb    = (unsigned short*)(ws + 134217728ull);  // 402,653,184
  unsigned short* attnout = (unsigned short*)(ws + 536870912ull);  // 134,217,728
  unsigned short* qkv_wb  = (unsigned short*)(ws + 671088640ull);  // 1,572,864
  unsigned short* proj_wb = (unsigned short*)(ws + 672661504ull);  // 524,288

  f32_to_bf16_vec4<<<2048, 256, 0, stream>>>(X, Xb, 67108864 / 4);
  f32_to_bf16_vec4<<<768, 256, 0, stream>>>(qkv_w, qkv_wb, 786432 / 4);
  f32_to_bf16_vec4<<<256, 256, 0, stream>>>(proj_w, proj_wb, 262144 / 4);

  // QKV: M=131072, N=1536, K=512 -> qkvb bf16 (ldc=1536), bias fused
  gemm_bt<true><<<dim3(12, 1024), 256, 0, stream>>>(Xb, qkv_wb, qkv_b, (void*)qkvb, 512, 1536);

  // attention: one wave per (b, h)
  attn_kernel<<<2048 * 16, 64, 0, stream>>>(qkvb, bias_table, mask, attnout);

  // proj: M=131072, N=512, K=512 -> d_out f32 (ldc=512), bias fused
  gemm_bt<false><<<dim3(4, 1024), 256, 0, stream>>>(attnout, proj_wb, proj_b, (void*)out, 512, 512);
}

// Round 2
// 793.759 us; speedup vs baseline: 1.2440x; 1.2440x over previous
//
#include <hip/hip_runtime.h>

typedef __bf16 bf16x8 __attribute__((ext_vector_type(8)));
typedef float f32x4 __attribute__((ext_vector_type(4)));

__device__ __forceinline__ unsigned short f2bf(float x) {
  union { float f; unsigned int u; } c; c.f = x;
  unsigned int r = c.u + 0x7FFFu + ((c.u >> 16) & 1u);
  return (unsigned short)(r >> 16);
}

// ---------------- convert f32 -> bf16 (vectorized) ----------------
__global__ __launch_bounds__(256) void f32_to_bf16_vec4(
    const float* __restrict__ in, unsigned short* __restrict__ out, int n4) {
  int i = blockIdx.x * blockDim.x + threadIdx.x;
  int stride = gridDim.x * blockDim.x;
  const float4* in4 = (const float4*)in;
  ushort4* out4 = (ushort4*)out;
  for (; i < n4; i += stride) {
    float4 f = in4[i];
    ushort4 u;
    u.x = f2bf(f.x); u.y = f2bf(f.y); u.z = f2bf(f.z); u.w = f2bf(f.w);
    out4[i] = u;
  }
}

#define GLOAD_LDS16(gp, lp)                                                          \
  __builtin_amdgcn_global_load_lds(                                                  \
      (const __attribute__((address_space(1))) unsigned int*)(uintptr_t)(gp),        \
      (__attribute__((address_space(3))) unsigned int*)(uintptr_t)(lp), 16, 0, 0)

// ---------------- 256x256 8-phase GEMM: C = A * B^T + bias ----------------
// A: MxK bf16 row-major, B: NxK bf16 row-major. K=512 fixed. 512 threads = 8 waves
// (2 M x 4 N). BK=64, double-buffered LDS (128 KiB), XOR-swizzled rows (slot^row&7),
// counted vmcnt(4), quadrant-matched prefetch units, setprio around MFMA clusters.
template <int NBN, bool BF16OUT>
__global__ __launch_bounds__(512, 2) void gemm256(
    const unsigned short* __restrict__ A,
    const unsigned short* __restrict__ B,
    const float* __restrict__ bias,
    void* __restrict__ Cv,
    int ldc) {
  constexpr int K = 512;
  constexpr int NT = K / 64;  // 8 K-tiles
  __shared__ __attribute__((aligned(128))) char lds[131072];  // A:[2][256][64] | B:[2][256][64]

  const int t = threadIdx.x;
  const int lane = t & 63;
  const int wid = t >> 6;
  const int wr = wid >> 2, wc = wid & 3;  // 2 x 4 waves
  const int lr = lane & 15, lg = lane >> 4;

  // bijective XCD swizzle (gridDim.x % 8 == 0)
  const int nwg = gridDim.x;
  const int cpx = nwg >> 3;
  const int wgid = (blockIdx.x & 7) * cpx + (blockIdx.x >> 3);
  const int bm = wgid / NBN, bn = wgid % NBN;
  const int m0 = bm * 256, n0 = bn * 256;

  const char* Ab = (const char*)(A + (size_t)m0 * K);
  const char* Bb = (const char*)(B + (size_t)n0 * K);

  const int r3 = t >> 3, ps = t & 7;

  // staging offsets: unit j, issue i (each issue = 64 rows, 512 thr x 16B)
  unsigned aoff[2][2], boff[2][2], adst[2][2], bdst[2][2];
#pragma unroll
  for (int j = 0; j < 2; ++j)
#pragma unroll
    for (int i = 0; i < 2; ++i) {
      const int rowA = i * 128 + j * 64 + r3;                       // UA_j rows
      aoff[j][i] = (unsigned)((rowA * K + ((ps ^ (rowA & 7)) << 3)) * 2);
      adst[j][i] = (unsigned)(rowA * 128 + ps * 16);
      const int rowB = i * 128 + ((r3 >> 5) << 6) + j * 32 + (r3 & 31);  // UB_j rows
      boff[j][i] = (unsigned)((rowB * K + ((ps ^ (rowB & 7)) << 3)) * 2);
      bdst[j][i] = (unsigned)(65536 + rowB * 128 + ps * 16);
    }

#define STAGE_A(j, tt, buf)                                                   \
  do {                                                                        \
    GLOAD_LDS16(Ab + aoff[j][0] + (tt)*128, lds + (buf)*32768 + adst[j][0]);  \
    GLOAD_LDS16(Ab + aoff[j][1] + (tt)*128, lds + (buf)*32768 + adst[j][1]);  \
  } while (0)
#define STAGE_B(j, tt, buf)                                                   \
  do {                                                                        \
    GLOAD_LDS16(Bb + boff[j][0] + (tt)*128, lds + (buf)*32768 + bdst[j][0]);  \
    GLOAD_LDS16(Bb + boff[j][1] + (tt)*128, lds + (buf)*32768 + bdst[j][1]);  \
  } while (0)

  // fragment read bases (swizzled slot depends only on lr,lg,kk)
  unsigned abase[2], bbase[2];
#pragma unroll
  for (int kk = 0; kk < 2; ++kk) {
    abase[kk] = (unsigned)((wr * 128 + lr) * 128 + (((kk * 4 + lg) ^ (lr & 7)) << 4));
    bbase[kk] = (unsigned)(65536 + (wc * 64 + lr) * 128 + (((kk * 4 + lg) ^ (lr & 7)) << 4));
  }

  f32x4 acc[8][4];
#pragma unroll
  for (int i = 0; i < 8; ++i)
#pragma unroll
    for (int j = 0; j < 4; ++j) acc[i][j] = f32x4{0.f, 0.f, 0.f, 0.f};

#define PHASE(QM, QN, BUF, STAGE_STMT, TAIL_STMT)                                            \
  do {                                                                                       \
    bf16x8 af[4][2], bfr[2][2];                                                              \
    _Pragma("unroll") for (int mt = 0; mt < 4; ++mt)                                         \
      _Pragma("unroll") for (int kk = 0; kk < 2; ++kk)                                       \
        af[mt][kk] = *(const bf16x8*)(lds + (BUF)*32768 + abase[kk] + (QM)*8192 + mt * 2048);\
    _Pragma("unroll") for (int nt = 0; nt < 2; ++nt)                                         \
      _Pragma("unroll") for (int kk = 0; kk < 2; ++kk)                                       \
        bfr[nt][kk] = *(const bf16x8*)(lds + (BUF)*32768 + bbase[kk] + (QN)*4096 + nt * 2048);\
    STAGE_STMT;                                                                              \
    __builtin_amdgcn_s_barrier();                                                            \
    asm volatile("s_waitcnt lgkmcnt(0)" ::: "memory");                                       \
    __builtin_amdgcn_sched_barrier(0);                                                       \
    __builtin_amdgcn_s_setprio(1);                                                           \
    _Pragma("unroll") for (int mt = 0; mt < 4; ++mt)                                         \
      _Pragma("unroll") for (int nt = 0; nt < 2; ++nt)                                       \
        _Pragma("unroll") for (int kk = 0; kk < 2; ++kk)                                     \
          acc[(QM)*4 + mt][(QN)*2 + nt] = __builtin_amdgcn_mfma_f32_16x16x32_bf16(           \
              af[mt][kk], bfr[nt][kk], acc[(QM)*4 + mt][(QN)*2 + nt], 0, 0, 0);              \
    __builtin_amdgcn_s_setprio(0);                                                           \
    TAIL_STMT;                                                                               \
    __builtin_amdgcn_s_barrier();                                                            \
  } while (0)

  // prologue: tile0 fully + UB0/UA1 of tile1; wait oldest 8 (tile0), 4 in flight
  STAGE_A(0, 0, 0); STAGE_B(0, 0, 0); STAGE_A(1, 0, 0); STAGE_B(1, 0, 0);
  STAGE_B(0, 1, 1); STAGE_A(1, 1, 1);
  asm volatile("s_waitcnt vmcnt(4)" ::: "memory");
  __builtin_amdgcn_s_barrier();

  // main loop. Quadrant order (0,0),(1,0),(1,1),(0,1).
  // Deaths in buffer b (tile tt): UB0 after p1, UA1 after p2, UA0/UB1 after p3.
  // Stage: p0->UA0(tt+1,b^1), p1->UB1(tt+1,b^1), p2->UB0(tt+2,b), p3->UA1(tt+2,b).
#pragma unroll
  for (int tt = 0; tt < NT; ++tt) {
    const int b = tt & 1;
    const int b1 = b ^ 1;
    PHASE(0, 0, b, if (tt + 1 < NT) STAGE_A(0, tt + 1, b1), (void)0);
    PHASE(1, 0, b, if (tt + 1 < NT) STAGE_B(1, tt + 1, b1), (void)0);
    PHASE(1, 1, b, if (tt + 2 < NT) STAGE_B(0, tt + 2, b), (void)0);
    if (tt + 2 < NT) {
      PHASE(0, 1, b, STAGE_A(1, tt + 2, b),
            asm volatile("s_waitcnt vmcnt(4)" ::: "memory"));
    } else if (tt + 1 < NT) {
      PHASE(0, 1, b, (void)0, asm volatile("s_waitcnt vmcnt(0)" ::: "memory"));
    } else {
      PHASE(0, 1, b, (void)0, (void)0);
    }
  }
#undef PHASE
#undef STAGE_A
#undef STAGE_B

  // epilogue
#pragma unroll
  for (int qm = 0; qm < 2; ++qm)
#pragma unroll
    for (int mt = 0; mt < 4; ++mt)
#pragma unroll
      for (int qn = 0; qn < 2; ++qn)
#pragma unroll
        for (int nt = 0; nt < 2; ++nt) {
          const int n = n0 + wc * 64 + qn * 32 + nt * 16 + lr;
          const float bv = bias[n];
          const f32x4 a4 = acc[qm * 4 + mt][qn * 2 + nt];
#pragma unroll
          for (int r = 0; r < 4; ++r) {
            const int m = m0 + wr * 128 + qm * 64 + mt * 16 + lg * 4 + r;
            const float v = a4[r] + bv;
            if constexpr (BF16OUT)
              ((unsigned short*)Cv)[(size_t)m * ldc + n] = f2bf(v);
            else
              ((float*)Cv)[(size_t)m * ldc + n] = v;
          }
        }
}

// ---------------- fused window attention: one wave per (window b, head h) ----------------
__global__ __launch_bounds__(64) void attn_kernel(
    const unsigned short* __restrict__ qkv,
    const float* __restrict__ bias_table,  // [127][16]
    const float* __restrict__ mask,        // [64][64][64]
    unsigned short* __restrict__ attn_out  // [B*64][512] bf16
) {
  const int bh = blockIdx.x;
  const int b = bh >> 4;
  const int h = bh & 15;
  const int lane = threadIdx.x;
  const int lr = lane & 15, lg = lane >> 4;

  __shared__ unsigned short Vt[32 * 72];
  __shared__ unsigned short Pl[64 * 72];

  const unsigned short* base = qkv + (size_t)b * 64 * 1536;

  const unsigned short* vp = base + (size_t)lane * 1536 + 1024 + h * 32;
  bf16x8 vr0 = ((const bf16x8*)vp)[0];
  bf16x8 vr1 = ((const bf16x8*)vp)[1];
  bf16x8 vr2 = ((const bf16x8*)vp)[2];
  bf16x8 vr3 = ((const bf16x8*)vp)[3];

  bf16x8 qf[4], kf[4];
#pragma unroll
  for (int mt = 0; mt < 4; ++mt)
    qf[mt] = *(const bf16x8*)(base + (size_t)(mt * 16 + lr) * 1536 + h * 32 + lg * 8);
#pragma unroll
  for (int nt = 0; nt < 4; ++nt)
    kf[nt] = *(const bf16x8*)(base + (size_t)(nt * 16 + lr) * 1536 + 512 + h * 32 + lg * 8);

  f32x4 s[4][4];
#pragma unroll
  for (int i = 0; i < 4; ++i)
#pragma unroll
    for (int j = 0; j < 4; ++j) s[i][j] = f32x4{0.f, 0.f, 0.f, 0.f};
#pragma unroll
  for (int mt = 0; mt < 4; ++mt)
#pragma unroll
    for (int nt = 0; nt < 4; ++nt)
      s[mt][nt] = __builtin_amdgcn_mfma_f32_16x16x32_bf16(qf[mt], kf[nt], s[mt][nt], 0, 0, 0);

  {
    __bf16* vt = (__bf16*)Vt;
#pragma unroll
    for (int d = 0; d < 8; ++d) {
      vt[(d)*72 + lane] = vr0[d];
      vt[(d + 8) * 72 + lane] = vr1[d];
      vt[(d + 16) * 72 + lane] = vr2[d];
      vt[(d + 24) * 72 + lane] = vr3[d];
    }
  }

  const float scale = 0.17677669529663687f;
  const float* mrow = mask + (size_t)(b & 63) * 4096;
  float rsum[4][4];
#pragma unroll
  for (int mt = 0; mt < 4; ++mt) {
#pragma unroll
    for (int r = 0; r < 4; ++r) {
      const int m = mt * 16 + lg * 4 + r;
      float v[4];
#pragma unroll
      for (int nt = 0; nt < 4; ++nt) {
        const int n = nt * 16 + lr;
        v[nt] = s[mt][nt][r] * scale + bias_table[(m - n + 63) * 16 + h] + mrow[m * 64 + n];
      }
      float mx = fmaxf(fmaxf(v[0], v[1]), fmaxf(v[2], v[3]));
      mx = fmaxf(mx, __shfl_xor(mx, 1, 64));
      mx = fmaxf(mx, __shfl_xor(mx, 2, 64));
      mx = fmaxf(mx, __shfl_xor(mx, 4, 64));
      mx = fmaxf(mx, __shfl_xor(mx, 8, 64));
      float sum = 0.f;
#pragma unroll
      for (int nt = 0; nt < 4; ++nt) {
        v[nt] = __expf(v[nt] - mx);
        sum += v[nt];
      }
      sum += __shfl_xor(sum, 1, 64);
      sum += __shfl_xor(sum, 2, 64);
      sum += __shfl_xor(sum, 4, 64);
      sum += __shfl_xor(sum, 8, 64);
      rsum[mt][r] = sum;
#pragma unroll
      for (int nt = 0; nt < 4; ++nt)
        Pl[m * 72 + nt * 16 + lr] = f2bf(v[nt]);
    }
  }

  __syncthreads();

  f32x4 o[4][2];
#pragma unroll
  for (int i = 0; i < 4; ++i)
#pragma unroll
    for (int j = 0; j < 2; ++j) o[i][j] = f32x4{0.f, 0.f, 0.f, 0.f};
#pragma unroll
  for (int ki = 0; ki < 2; ++ki) {
    bf16x8 pa[4], vb[2];
#pragma unroll
    for (int mt = 0; mt < 4; ++mt)
      pa[mt] = *(const bf16x8*)(Pl + (mt * 16 + lr) * 72 + ki * 32 + lg * 8);
#pragma unroll
    for (int dt = 0; dt < 2; ++dt)
      vb[dt] = *(const bf16x8*)(Vt + (dt * 16 + lr) * 72 + ki * 32 + lg * 8);
#pragma unroll
    for (int mt = 0; mt < 4; ++mt)
#pragma unroll
      for (int dt = 0; dt < 2; ++dt)
        o[mt][dt] = __builtin_amdgcn_mfma_f32_16x16x32_bf16(pa[mt], vb[dt], o[mt][dt], 0, 0, 0);
  }

#pragma unroll
  for (int mt = 0; mt < 4; ++mt) {
#pragma unroll
    for (int r = 0; r < 4; ++r) {
      const float rinv = 1.0f / rsum[mt][r];
      const int m = mt * 16 + lg * 4 + r;
#pragma unroll
      for (int dt = 0; dt < 2; ++dt) {
        const int d = dt * 16 + lr;
        attn_out[(size_t)(b * 64 + m) * 512 + h * 32 + d] = f2bf(o[mt][dt][r] * rinv);
      }
    }
  }
}

// ---------------- launch ----------------
extern "C" void kernel_launch(void* const* d_in, const int* in_sizes, int n_in,
                              void* d_out, int out_size, void* d_ws, size_t ws_size,
                              hipStream_t stream) {
  const float* X = (const float*)d_in[0];
  const float* mask = (const float*)d_in[1];
  const float* qkv_w = (const float*)d_in[2];
  const float* qkv_b = (const float*)d_in[3];
  const float* proj_w = (const float*)d_in[4];
  const float* proj_b = (const float*)d_in[5];
  const float* bias_table = (const float*)d_in[6];
  float* out = (float*)d_out;
  char* ws = (char*)d_ws;

  unsigned short* Xb      = (unsigned short*)(ws);                 // 134,217,728
  unsigned short* qkvb    = (unsigned short*)(ws + 134217728ull);  // 402,653,184
  unsigned short* attnout = (unsigned short*)(ws + 536870912ull);  // 134,217,728
  unsigned short* qkv_wb  = (unsigned short*)(ws + 671088640ull);  // 1,572,864
  unsigned short* proj_wb = (unsigned short*)(ws + 672661504ull);  // 524,288

  f32_to_bf16_vec4<<<2048, 256, 0, stream>>>(X, Xb, 67108864 / 4);
  f32_to_bf16_vec4<<<768, 256, 0, stream>>>(qkv_w, qkv_wb, 786432 / 4);
  f32_to_bf16_vec4<<<256, 256, 0, stream>>>(proj_w, proj_wb, 262144 / 4);

  // QKV: M=131072, N=1536, K=512 -> qkvb bf16 (ldc=1536); grid 512*6 = 3072 (%8==0)
  gemm256<6, true><<<3072, 512, 0, stream>>>(Xb, qkv_wb, qkv_b, (void*)qkvb, 1536);

  // attention: one wave per (b, h)
  attn_kernel<<<2048 * 16, 64, 0, stream>>>(qkvb, bias_table, mask, attnout);

  // proj: M=131072, N=512, K=512 -> d_out f32 (ldc=512); grid 512*2 = 1024 (%8==0)
  gemm256<2, false><<<1024, 512, 0, stream>>>(attnout, proj_wb, proj_b, (void*)out, 512);
}

// Round 3
// 606.814 us; speedup vs baseline: 1.6273x; 1.3081x over previous
//
#include <hip/hip_runtime.h>

typedef __bf16 bf16x8 __attribute__((ext_vector_type(8)));
typedef float f32x4 __attribute__((ext_vector_type(4)));

__device__ __forceinline__ unsigned short f2bf(float x) {
  union { float f; unsigned int u; } c; c.f = x;
  unsigned int r = c.u + 0x7FFFu + ((c.u >> 16) & 1u);
  return (unsigned short)(r >> 16);
}

// ---------------- convert f32 -> bf16 (vectorized) ----------------
__global__ __launch_bounds__(256) void f32_to_bf16_vec4(
    const float* __restrict__ in, unsigned short* __restrict__ out, int n4) {
  int i = blockIdx.x * blockDim.x + threadIdx.x;
  int stride = gridDim.x * blockDim.x;
  const float4* in4 = (const float4*)in;
  ushort4* out4 = (ushort4*)out;
  for (; i < n4; i += stride) {
    float4 f = in4[i];
    ushort4 u;
    u.x = f2bf(f.x); u.y = f2bf(f.y); u.z = f2bf(f.z); u.w = f2bf(f.w);
    out4[i] = u;
  }
}

// ---------------- fuse rel-pos bias + window mask: M[w][h][q][k] ----------------
__global__ __launch_bounds__(256) void build_bias_mask(
    const float* __restrict__ bias_table,  // [127][16]
    const float* __restrict__ mask,        // [64][64][64]
    float* __restrict__ M) {               // [64][16][64][64]
  const int idx = blockIdx.x * 256 + threadIdx.x;
  const int k = idx & 63, q = (idx >> 6) & 63, h = (idx >> 12) & 15, w = idx >> 16;
  M[idx] = bias_table[(q - k + 63) * 16 + h] + mask[(w * 64 + q) * 64 + k];
}

#define GLOAD_LDS16(gp, lp)                                                          \
  __builtin_amdgcn_global_load_lds(                                                  \
      (const __attribute__((address_space(1))) unsigned int*)(uintptr_t)(gp),        \
      (__attribute__((address_space(3))) unsigned int*)(uintptr_t)(lp), 16, 0, 0)

// ---------------- 256x256 8-phase GEMM: C = A * B^T + bias ----------------
// EPI: 0 = f32 row-major out (C0, ldc); 2 = qkv-split head-blocked bf16 out (C0=Q,C1=K,C2=V)
template <int NBN, int EPI>
__global__ __launch_bounds__(512, 2) void gemm256(
    const unsigned short* __restrict__ A,
    const unsigned short* __restrict__ B,
    const float* __restrict__ bias,
    void* __restrict__ C0, void* __restrict__ C1, void* __restrict__ C2,
    int ldc) {
  constexpr int K = 512;
  constexpr int NT = K / 64;  // 8 K-tiles
  __shared__ __attribute__((aligned(128))) char lds[131072];

  const int t = threadIdx.x;
  const int lane = t & 63;
  const int wid = t >> 6;
  const int wr = wid >> 2, wc = wid & 3;
  const int lr = lane & 15, lg = lane >> 4;

  const int nwg = gridDim.x;
  const int cpx = nwg >> 3;
  const int wgid = (blockIdx.x & 7) * cpx + (blockIdx.x >> 3);
  const int bm = wgid / NBN, bn = wgid % NBN;
  const int m0 = bm * 256, n0 = bn * 256;

  const char* Ab = (const char*)(A + (size_t)m0 * K);
  const char* Bb = (const char*)(B + (size_t)n0 * K);

  const int r3 = t >> 3, ps = t & 7;

  unsigned aoff[2][2], boff[2][2], adst[2][2], bdst[2][2];
#pragma unroll
  for (int j = 0; j < 2; ++j)
#pragma unroll
    for (int i = 0; i < 2; ++i) {
      const int rowA = i * 128 + j * 64 + r3;
      aoff[j][i] = (unsigned)((rowA * K + ((ps ^ (rowA & 7)) << 3)) * 2);
      adst[j][i] = (unsigned)(rowA * 128 + ps * 16);
      const int rowB = i * 128 + ((r3 >> 5) << 6) + j * 32 + (r3 & 31);
      boff[j][i] = (unsigned)((rowB * K + ((ps ^ (rowB & 7)) << 3)) * 2);
      bdst[j][i] = (unsigned)(65536 + rowB * 128 + ps * 16);
    }

#define STAGE_A(j, tt, buf)                                                   \
  do {                                                                        \
    GLOAD_LDS16(Ab + aoff[j][0] + (tt)*128, lds + (buf)*32768 + adst[j][0]);  \
    GLOAD_LDS16(Ab + aoff[j][1] + (tt)*128, lds + (buf)*32768 + adst[j][1]);  \
  } while (0)
#define STAGE_B(j, tt, buf)                                                   \
  do {                                                                        \
    GLOAD_LDS16(Bb + boff[j][0] + (tt)*128, lds + (buf)*32768 + bdst[j][0]);  \
    GLOAD_LDS16(Bb + boff[j][1] + (tt)*128, lds + (buf)*32768 + bdst[j][1]);  \
  } while (0)

  unsigned abase[2], bbase[2];
#pragma unroll
  for (int kk = 0; kk < 2; ++kk) {
    abase[kk] = (unsigned)((wr * 128 + lr) * 128 + (((kk * 4 + lg) ^ (lr & 7)) << 4));
    bbase[kk] = (unsigned)(65536 + (wc * 64 + lr) * 128 + (((kk * 4 + lg) ^ (lr & 7)) << 4));
  }

  f32x4 acc[8][4];
#pragma unroll
  for (int i = 0; i < 8; ++i)
#pragma unroll
    for (int j = 0; j < 4; ++j) acc[i][j] = f32x4{0.f, 0.f, 0.f, 0.f};

#define PHASE(QM, QN, BUF, STAGE_STMT, TAIL_STMT)                                            \
  do {                                                                                       \
    bf16x8 af[4][2], bfr[2][2];                                                              \
    _Pragma("unroll") for (int mt = 0; mt < 4; ++mt)                                         \
      _Pragma("unroll") for (int kk = 0; kk < 2; ++kk)                                       \
        af[mt][kk] = *(const bf16x8*)(lds + (BUF)*32768 + abase[kk] + (QM)*8192 + mt * 2048);\
    _Pragma("unroll") for (int nt = 0; nt < 2; ++nt)                                         \
      _Pragma("unroll") for (int kk = 0; kk < 2; ++kk)                                       \
        bfr[nt][kk] = *(const bf16x8*)(lds + (BUF)*32768 + bbase[kk] + (QN)*4096 + nt * 2048);\
    STAGE_STMT;                                                                              \
    __builtin_amdgcn_s_barrier();                                                            \
    asm volatile("s_waitcnt lgkmcnt(0)" ::: "memory");                                       \
    __builtin_amdgcn_sched_barrier(0);                                                       \
    __builtin_amdgcn_s_setprio(1);                                                           \
    _Pragma("unroll") for (int mt = 0; mt < 4; ++mt)                                         \
      _Pragma("unroll") for (int nt = 0; nt < 2; ++nt)                                       \
        _Pragma("unroll") for (int kk = 0; kk < 2; ++kk)                                     \
          acc[(QM)*4 + mt][(QN)*2 + nt] = __builtin_amdgcn_mfma_f32_16x16x32_bf16(           \
              af[mt][kk], bfr[nt][kk], acc[(QM)*4 + mt][(QN)*2 + nt], 0, 0, 0);              \
    __builtin_amdgcn_s_setprio(0);                                                           \
    TAIL_STMT;                                                                               \
    __builtin_amdgcn_s_barrier();                                                            \
  } while (0)

  STAGE_A(0, 0, 0); STAGE_B(0, 0, 0); STAGE_A(1, 0, 0); STAGE_B(1, 0, 0);
  STAGE_B(0, 1, 1); STAGE_A(1, 1, 1);
  asm volatile("s_waitcnt vmcnt(4)" ::: "memory");
  __builtin_amdgcn_s_barrier();

#pragma unroll
  for (int tt = 0; tt < NT; ++tt) {
    const int b = tt & 1;
    const int b1 = b ^ 1;
    PHASE(0, 0, b, if (tt + 1 < NT) STAGE_A(0, tt + 1, b1), (void)0);
    PHASE(1, 0, b, if (tt + 1 < NT) STAGE_B(1, tt + 1, b1), (void)0);
    PHASE(1, 1, b, if (tt + 2 < NT) STAGE_B(0, tt + 2, b), (void)0);
    if (tt + 2 < NT) {
      PHASE(0, 1, b, STAGE_A(1, tt + 2, b),
            asm volatile("s_waitcnt vmcnt(4)" ::: "memory"));
    } else if (tt + 1 < NT) {
      PHASE(0, 1, b, (void)0, asm volatile("s_waitcnt vmcnt(0)" ::: "memory"));
    } else {
      PHASE(0, 1, b, (void)0, (void)0);
    }
  }
#undef PHASE
#undef STAGE_A
#undef STAGE_B

#pragma unroll
  for (int qm = 0; qm < 2; ++qm)
#pragma unroll
    for (int mt = 0; mt < 4; ++mt)
#pragma unroll
      for (int qn = 0; qn < 2; ++qn)
#pragma unroll
        for (int nt = 0; nt < 2; ++nt) {
          const int n = n0 + wc * 64 + qn * 32 + nt * 16 + lr;
          const float bv = bias[n];
          const f32x4 a4 = acc[qm * 4 + mt][qn * 2 + nt];
          if constexpr (EPI == 2) {
            const int part = n >> 9;
            unsigned short* dst = part == 0 ? (unsigned short*)C0
                                 : (part == 1 ? (unsigned short*)C1 : (unsigned short*)C2);
            const float sc = (part == 0) ? 0.17677669529663687f : 1.0f;
            const int hh = (n >> 5) & 15, dd = n & 31;
#pragma unroll
            for (int r = 0; r < 4; ++r) {
              const int m = m0 + wr * 128 + qm * 64 + mt * 16 + lg * 4 + r;
              dst[((size_t)((m >> 6) * 16 + hh) * 64 + (m & 63)) * 32 + dd] =
                  f2bf((a4[r] + bv) * sc);
            }
          } else {
#pragma unroll
            for (int r = 0; r < 4; ++r) {
              const int m = m0 + wr * 128 + qm * 64 + mt * 16 + lg * 4 + r;
              ((float*)C0)[(size_t)m * ldc + n] = a4[r] + bv;
            }
          }
        }
}

// ---------------- fused window attention v3: head-blocked inputs, per-q-tile chain ----------------
// 128 threads = 2 waves, wave w handles (b,h) = blockIdx.x*2+w. No barriers (per-wave LDS).
__global__ __launch_bounds__(128) void attn_kernel(
    const unsigned short* __restrict__ Qh,  // [32768][64][32] bf16, pre-scaled
    const unsigned short* __restrict__ Kh,  // [32768][64][32]
    const unsigned short* __restrict__ Vh,  // [32768][64][32]
    const float* __restrict__ M,            // [64][16][64][64] fused bias+mask
    unsigned short* __restrict__ attn_out   // [131072][512] bf16, col = h*32+d
) {
  const int wv = threadIdx.x >> 6;
  const int bh = blockIdx.x * 2 + wv;
  const int b = bh >> 4, h = bh & 15;
  const int lane = threadIdx.x & 63;
  const int lr = lane & 15, lg = lane >> 4;

  __shared__ unsigned short VtS[2][32 * 72];  // V^T per wave: [d][k], stride 72
  __shared__ unsigned short PlS[2][16 * 72];  // P-slice per wave: [16 q][k]
  unsigned short* Vt = VtS[wv];
  unsigned short* Pl = PlS[wv];

  const unsigned short* qb = Qh + (size_t)bh * 2048;
  const unsigned short* kb = Kh + (size_t)bh * 2048;
  const unsigned short* vg = Vh + (size_t)bh * 2048;

  // coalesced global loads (row stride 64B)
  bf16x8 vr[4];
#pragma unroll
  for (int i = 0; i < 4; ++i) vr[i] = ((const bf16x8*)(vg + lane * 32))[i];
  bf16x8 kf[4], qf[4];
#pragma unroll
  for (int nt = 0; nt < 4; ++nt)
    kf[nt] = *(const bf16x8*)(kb + (nt * 16 + lr) * 32 + lg * 8);
#pragma unroll
  for (int mt = 0; mt < 4; ++mt)
    qf[mt] = *(const bf16x8*)(qb + (mt * 16 + lr) * 32 + lg * 8);

  // transpose V into LDS, then load B-fragments once
  {
    __bf16* vt = (__bf16*)Vt;
#pragma unroll
    for (int d = 0; d < 8; ++d) {
      vt[(d)*72 + lane] = vr[0][d];
      vt[(d + 8) * 72 + lane] = vr[1][d];
      vt[(d + 16) * 72 + lane] = vr[2][d];
      vt[(d + 24) * 72 + lane] = vr[3][d];
    }
  }
  bf16x8 vfrag[2][2];
#pragma unroll
  for (int dt = 0; dt < 2; ++dt)
#pragma unroll
    for (int ki = 0; ki < 2; ++ki)
      vfrag[dt][ki] = *(const bf16x8*)(Vt + (dt * 16 + lr) * 72 + ki * 32 + lg * 8);

  const float* Mb = M + (size_t)((b & 63) * 16 + h) * 4096;

  f32x4 o[4][2];
#pragma unroll
  for (int i = 0; i < 4; ++i)
#pragma unroll
    for (int j = 0; j < 2; ++j) o[i][j] = f32x4{0.f, 0.f, 0.f, 0.f};
  float rinv[4][4];

#pragma unroll
  for (int mt = 0; mt < 4; ++mt) {
    // prefetch fused bias+mask for this q-tile (coalesced f32)
    float mv[4][4];
#pragma unroll
    for (int r = 0; r < 4; ++r)
#pragma unroll
      for (int nt = 0; nt < 4; ++nt)
        mv[r][nt] = Mb[(mt * 16 + lg * 4 + r) * 64 + nt * 16 + lr];

    f32x4 s[4];
#pragma unroll
    for (int nt = 0; nt < 4; ++nt) s[nt] = f32x4{0.f, 0.f, 0.f, 0.f};
#pragma unroll
    for (int nt = 0; nt < 4; ++nt)
      s[nt] = __builtin_amdgcn_mfma_f32_16x16x32_bf16(qf[mt], kf[nt], s[nt], 0, 0, 0);

    // softmax over 64 keys for rows m = mt*16 + lg*4 + r
#pragma unroll
    for (int r = 0; r < 4; ++r) {
      float v[4];
#pragma unroll
      for (int nt = 0; nt < 4; ++nt) v[nt] = s[nt][r] + mv[r][nt];
      float mx = fmaxf(fmaxf(v[0], v[1]), fmaxf(v[2], v[3]));
      mx = fmaxf(mx, __shfl_xor(mx, 1, 64));
      mx = fmaxf(mx, __shfl_xor(mx, 2, 64));
      mx = fmaxf(mx, __shfl_xor(mx, 4, 64));
      mx = fmaxf(mx, __shfl_xor(mx, 8, 64));
      float sum = 0.f;
#pragma unroll
      for (int nt = 0; nt < 4; ++nt) {
        v[nt] = __expf(v[nt] - mx);
        sum += v[nt];
      }
      sum += __shfl_xor(sum, 1, 64);
      sum += __shfl_xor(sum, 2, 64);
      sum += __shfl_xor(sum, 4, 64);
      sum += __shfl_xor(sum, 8, 64);
      rinv[mt][r] = __builtin_amdgcn_rcpf(sum);
#pragma unroll
      for (int nt = 0; nt < 4; ++nt)
        Pl[(lg * 4 + r) * 72 + nt * 16 + lr] = f2bf(v[nt]);
    }

    // PV for this q-tile (in-order DS pipe: reads follow writes, same wave)
    bf16x8 pa[2];
#pragma unroll
    for (int ki = 0; ki < 2; ++ki)
      pa[ki] = *(const bf16x8*)(Pl + lr * 72 + ki * 32 + lg * 8);
#pragma unroll
    for (int dt = 0; dt < 2; ++dt)
#pragma unroll
      for (int ki = 0; ki < 2; ++ki)
        o[mt][dt] = __builtin_amdgcn_mfma_f32_16x16x32_bf16(pa[ki], vfrag[dt][ki], o[mt][dt], 0, 0, 0);
  }

#pragma unroll
  for (int mt = 0; mt < 4; ++mt) {
#pragma unroll
    for (int r = 0; r < 4; ++r) {
      const int m = mt * 16 + lg * 4 + r;
      const float ri = rinv[mt][r];
#pragma unroll
      for (int dt = 0; dt < 2; ++dt) {
        const int d = dt * 16 + lr;
        attn_out[(size_t)(b * 64 + m) * 512 + h * 32 + d] = f2bf(o[mt][dt][r] * ri);
      }
    }
  }
}

// ---------------- launch ----------------
extern "C" void kernel_launch(void* const* d_in, const int* in_sizes, int n_in,
                              void* d_out, int out_size, void* d_ws, size_t ws_size,
                              hipStream_t stream) {
  const float* X = (const float*)d_in[0];
  const float* mask = (const float*)d_in[1];
  const float* qkv_w = (const float*)d_in[2];
  const float* qkv_b = (const float*)d_in[3];
  const float* proj_w = (const float*)d_in[4];
  const float* proj_b = (const float*)d_in[5];
  const float* bias_table = (const float*)d_in[6];
  float* out = (float*)d_out;
  char* ws = (char*)d_ws;

  // workspace layout (bytes)
  unsigned short* Xb      = (unsigned short*)(ws);                 // 134,217,728
  unsigned short* Qh      = (unsigned short*)(ws + 134217728ull);  // 134,217,728
  unsigned short* Kh      = (unsigned short*)(ws + 268435456ull);  // 134,217,728
  unsigned short* Vh      = (unsigned short*)(ws + 402653184ull);  // 134,217,728
  unsigned short* attnout = (unsigned short*)(ws + 536870912ull);  // 134,217,728
  unsigned short* qkv_wb  = (unsigned short*)(ws + 671088640ull);  // 1,572,864
  unsigned short* proj_wb = (unsigned short*)(ws + 672661504ull);  // 524,288
  float*          Mf      = (float*)(ws + 673185792ull);           // 16,777,216

  f32_to_bf16_vec4<<<2048, 256, 0, stream>>>(X, Xb, 67108864 / 4);
  f32_to_bf16_vec4<<<768, 256, 0, stream>>>(qkv_w, qkv_wb, 786432 / 4);
  f32_to_bf16_vec4<<<256, 256, 0, stream>>>(proj_w, proj_wb, 262144 / 4);
  build_bias_mask<<<16384, 256, 0, stream>>>(bias_table, mask, Mf);

  // QKV: M=131072, N=1536, K=512 -> head-blocked Q/K/V bf16; grid 512*6 = 3072
  gemm256<6, 2><<<3072, 512, 0, stream>>>(Xb, qkv_wb, qkv_b, (void*)Qh, (void*)Kh, (void*)Vh, 1536);

  // attention: 2 waves per block, wave per (b,h)
  attn_kernel<<<16384, 128, 0, stream>>>(Qh, Kh, Vh, Mf, attnout);

  // proj: M=131072, N=512, K=512 -> d_out f32; grid 512*2 = 1024
  gemm256<2, 0><<<1024, 512, 0, stream>>>(attnout, proj_wb, proj_b, (void*)out, nullptr, nullptr, 512);
}

// Round 4
// 595.998 us; speedup vs baseline: 1.6568x; 1.0181x over previous
//
#include <hip/hip_runtime.h>

typedef __bf16 bf16x8 __attribute__((ext_vector_type(8)));
typedef float f32x4 __attribute__((ext_vector_type(4)));
typedef float f32x16 __attribute__((ext_vector_type(16)));

__device__ __forceinline__ unsigned short f2bf(float x) {
  union { float f; unsigned int u; } c; c.f = x;
  unsigned int r = c.u + 0x7FFFu + ((c.u >> 16) & 1u);
  return (unsigned short)(r >> 16);
}

// ---------------- convert f32 -> bf16 (vectorized) ----------------
__global__ __launch_bounds__(256) void f32_to_bf16_vec4(
    const float* __restrict__ in, unsigned short* __restrict__ out, int n4) {
  int i = blockIdx.x * blockDim.x + threadIdx.x;
  int stride = gridDim.x * blockDim.x;
  const float4* in4 = (const float4*)in;
  ushort4* out4 = (ushort4*)out;
  for (; i < n4; i += stride) {
    float4 f = in4[i];
    ushort4 u;
    u.x = f2bf(f.x); u.y = f2bf(f.y); u.z = f2bf(f.z); u.w = f2bf(f.w);
    out4[i] = u;
  }
}

// ---------------- fuse rel-pos bias + window mask: M[w][h][q][k] ----------------
__global__ __launch_bounds__(256) void build_bias_mask(
    const float* __restrict__ bias_table,  // [127][16]
    const float* __restrict__ mask,        // [64][64][64]
    float* __restrict__ M) {               // [64][16][64][64]
  const int idx = blockIdx.x * 256 + threadIdx.x;
  const int k = idx & 63, q = (idx >> 6) & 63, h = (idx >> 12) & 15, w = idx >> 16;
  M[idx] = bias_table[(q - k + 63) * 16 + h] + mask[(w * 64 + q) * 64 + k];
}

#define GLOAD_LDS16(gp, lp)                                                          \
  __builtin_amdgcn_global_load_lds(                                                  \
      (const __attribute__((address_space(1))) unsigned int*)(uintptr_t)(gp),        \
      (__attribute__((address_space(3))) unsigned int*)(uintptr_t)(lp), 16, 0, 0)

// ---------------- 256x256 GEMM, 32x32x16 MFMA, 4 phases/K-tile: C = A*B^T + bias ----------------
// A: MxK bf16 row-major, B: NxK bf16 row-major. K=512. 512 threads = 8 waves (2M x 4N),
// wave tile 128x64 = 4 mt(32r) x 2 nt(32c). Per phase: read A-strip (4 b128) [+ B 8 b128 in p0],
// 8 MFMA. B-frags register-held across the K-tile. LDS XOR-swizzle, counted vmcnt(6).
// EPI: 0 = f32 row-major out (C0, ldc); 2 = qkv-split head-blocked bf16 out (C0=Q,C1=K,C2=V)
template <int NBN, int EPI>
__global__ __launch_bounds__(512, 2) void gemm256(
    const unsigned short* __restrict__ A,
    const unsigned short* __restrict__ B,
    const float* __restrict__ bias,
    void* __restrict__ C0, void* __restrict__ C1, void* __restrict__ C2,
    int ldc) {
  constexpr int K = 512;
  constexpr int NT = K / 64;  // 8 K-tiles
  __shared__ __attribute__((aligned(128))) char lds[131072];

  const int t = threadIdx.x;
  const int lane = t & 63;
  const int wid = t >> 6;
  const int wr = wid >> 2, wc = wid & 3;
  const int l31 = lane & 31, hi = lane >> 5;

  const int nwg = gridDim.x;
  const int cpx = nwg >> 3;
  const int wgid = (blockIdx.x & 7) * cpx + (blockIdx.x >> 3);
  const int bm = wgid / NBN, bn = wgid % NBN;
  const int m0 = bm * 256, n0 = bn * 256;

  const char* Ab = (const char*)(A + (size_t)m0 * K);
  const char* Bb = (const char*)(B + (size_t)n0 * K);

  const int r3 = t >> 3, ps = t & 7;

  // staging offsets: unit j, issue i (each issue = 64 rows, 512 thr x 16B)
  unsigned aoff[2][2], boff[2][2], adst[2][2], bdst[2][2];
#pragma unroll
  for (int j = 0; j < 2; ++j)
#pragma unroll
    for (int i = 0; i < 2; ++i) {
      const int rowA = i * 128 + j * 64 + r3;                            // UA_j
      aoff[j][i] = (unsigned)((rowA * K + ((ps ^ (rowA & 7)) << 3)) * 2);
      adst[j][i] = (unsigned)(rowA * 128 + ps * 16);
      const int rowB = i * 128 + ((r3 >> 5) << 6) + j * 32 + (r3 & 31);  // UB_j
      boff[j][i] = (unsigned)((rowB * K + ((ps ^ (rowB & 7)) << 3)) * 2);
      bdst[j][i] = (unsigned)(65536 + rowB * 128 + ps * 16);
    }

#define STAGE_A(j, tt, buf)                                                   \
  do {                                                                        \
    GLOAD_LDS16(Ab + aoff[j][0] + (tt)*128, lds + (buf)*32768 + adst[j][0]);  \
    GLOAD_LDS16(Ab + aoff[j][1] + (tt)*128, lds + (buf)*32768 + adst[j][1]);  \
  } while (0)
#define STAGE_B(j, tt, buf)                                                   \
  do {                                                                        \
    GLOAD_LDS16(Bb + boff[j][0] + (tt)*128, lds + (buf)*32768 + bdst[j][0]);  \
    GLOAD_LDS16(Bb + boff[j][1] + (tt)*128, lds + (buf)*32768 + bdst[j][1]);  \
  } while (0)

  // fragment read bases: A row = wr*128 + mt*32 + l31, k-slot = kk*2 + hi (swizzled)
  unsigned abase[4], bbase[4];
#pragma unroll
  for (int kk = 0; kk < 4; ++kk) {
    const unsigned swz = (unsigned)((((kk * 2 + hi) ^ (lane & 7)) << 4));
    abase[kk] = (unsigned)((wr * 128 + l31) * 128) + swz;
    bbase[kk] = (unsigned)(65536 + (wc * 64 + l31) * 128) + swz;
  }

  f32x16 acc[4][2];
#pragma unroll
  for (int i = 0; i < 4; ++i)
#pragma unroll
    for (int j = 0; j < 2; ++j)
#pragma unroll
      for (int r = 0; r < 16; ++r) acc[i][j][r] = 0.f;

  // phase macro: A-strip MT reads + stage + barrier/lgkm/schedbar + 8 MFMA + tail + barrier
#define PHASEM(MT, BUF, PRE_STMT, STAGE_STMT, TAIL_STMT)                          \
  do {                                                                            \
    bf16x8 af[4];                                                                 \
    PRE_STMT;                                                                     \
    _Pragma("unroll") for (int kk = 0; kk < 4; ++kk)                              \
      af[kk] = *(const bf16x8*)(lds + (BUF)*32768 + abase[kk] + (MT)*4096);       \
    STAGE_STMT;                                                                   \
    __builtin_amdgcn_s_barrier();                                                 \
    asm volatile("s_waitcnt lgkmcnt(0)" ::: "memory");                            \
    __builtin_amdgcn_sched_barrier(0);                                            \
    __builtin_amdgcn_s_setprio(1);                                                \
    _Pragma("unroll") for (int kk = 0; kk < 4; ++kk)                              \
      acc[MT][0] = __builtin_amdgcn_mfma_f32_32x32x16_bf16(af[kk], bf0[kk],       \
                                                           acc[MT][0], 0, 0, 0); \
    _Pragma("unroll") for (int kk = 0; kk < 4; ++kk)                              \
      acc[MT][1] = __builtin_amdgcn_mfma_f32_32x32x16_bf16(af[kk], bf1[kk],       \
                                                           acc[MT][1], 0, 0, 0); \
    __builtin_amdgcn_s_setprio(0);                                                \
    TAIL_STMT;                                                                    \
    __builtin_amdgcn_s_barrier();                                                 \
  } while (0)

  // prologue: tile0 all units (8 loads) + UB0/UB1/UA0 of tile1 (6 loads); 6 in flight after wait
  STAGE_A(0, 0, 0); STAGE_A(1, 0, 0); STAGE_B(0, 0, 0); STAGE_B(1, 0, 0);
  STAGE_B(0, 1, 1); STAGE_B(1, 1, 1); STAGE_A(0, 1, 1);
  asm volatile("s_waitcnt vmcnt(6)" ::: "memory");
  __builtin_amdgcn_s_barrier();

  // Deaths in buffer b (tile tt): UB0/UB1 after p0, UA0 after p1, UA1 after p3.
  // Stage: p0->UA1(t+1,b^1), p1->UB0(t+2,b), p2->UB1(t+2,b), p3->UA0(t+2,b); vmcnt(6) at p3.
#pragma unroll
  for (int tt = 0; tt < NT; ++tt) {
    const int buf = tt & 1;
    const int nb = buf ^ 1;
    bf16x8 bf0[4], bf1[4];
    PHASEM(0, buf,
           {
             _Pragma("unroll") for (int kk = 0; kk < 4; ++kk) {
               bf0[kk] = *(const bf16x8*)(lds + buf * 32768 + bbase[kk]);
               bf1[kk] = *(const bf16x8*)(lds + buf * 32768 + bbase[kk] + 4096);
             }
           },
           if (tt + 1 < NT) STAGE_A(1, tt + 1, nb), (void)0);
    PHASEM(1, buf, (void)0, if (tt + 2 < NT) STAGE_B(0, tt + 2, buf), (void)0);
    PHASEM(2, buf, (void)0, if (tt + 2 < NT) STAGE_B(1, tt + 2, buf), (void)0);
    if (tt + 2 < NT) {
      PHASEM(3, buf, (void)0, STAGE_A(0, tt + 2, buf),
             asm volatile("s_waitcnt vmcnt(6)" ::: "memory"));
    } else if (tt + 1 < NT) {
      PHASEM(3, buf, (void)0, (void)0,
             asm volatile("s_waitcnt vmcnt(0)" ::: "memory"));
    } else {
      PHASEM(3, buf, (void)0, (void)0, (void)0);
    }
  }
#undef PHASEM
#undef STAGE_A
#undef STAGE_B

  // epilogue: 32x32 C/D layout: col = l31, row = (r&3) + 8*(r>>2) + 4*hi
#pragma unroll
  for (int mt = 0; mt < 4; ++mt) {
#pragma unroll
    for (int nt = 0; nt < 2; ++nt) {
      const int n = n0 + wc * 64 + nt * 32 + l31;
      const float bv = bias[n];
      const f32x16 a16 = acc[mt][nt];
      if constexpr (EPI == 2) {
        const int part = n >> 9;
        unsigned short* dst = part == 0 ? (unsigned short*)C0
                               : (part == 1 ? (unsigned short*)C1 : (unsigned short*)C2);
        const float sc = (part == 0) ? 0.17677669529663687f : 1.0f;
        const int hh = (n >> 5) & 15, dd = n & 31;
#pragma unroll
        for (int r = 0; r < 16; ++r) {
          const int m = m0 + wr * 128 + mt * 32 + (r & 3) + 8 * (r >> 2) + 4 * hi;
          dst[((size_t)((m >> 6) * 16 + hh) * 64 + (m & 63)) * 32 + dd] =
              f2bf((a16[r] + bv) * sc);
        }
      } else {
#pragma unroll
        for (int r = 0; r < 16; ++r) {
          const int m = m0 + wr * 128 + mt * 32 + (r & 3) + 8 * (r >> 2) + 4 * hi;
          ((float*)C0)[(size_t)m * ldc + n] = a16[r] + bv;
        }
      }
    }
  }
}

// ---------------- fused window attention v3: head-blocked inputs, per-q-tile chain ----------------
// 128 threads = 2 waves, wave w handles (b,h) = blockIdx.x*2+w. No barriers (per-wave LDS).
__global__ __launch_bounds__(128) void attn_kernel(
    const unsigned short* __restrict__ Qh,  // [32768][64][32] bf16, pre-scaled
    const unsigned short* __restrict__ Kh,  // [32768][64][32]
    const unsigned short* __restrict__ Vh,  // [32768][64][32]
    const float* __restrict__ M,            // [64][16][64][64] fused bias+mask
    unsigned short* __restrict__ attn_out   // [131072][512] bf16, col = h*32+d
) {
  const int wv = threadIdx.x >> 6;
  const int bh = blockIdx.x * 2 + wv;
  const int b = bh >> 4, h = bh & 15;
  const int lane = threadIdx.x & 63;
  const int lr = lane & 15, lg = lane >> 4;

  __shared__ unsigned short VtS[2][32 * 72];  // V^T per wave: [d][k], stride 72
  __shared__ unsigned short PlS[2][16 * 72];  // P-slice per wave: [16 q][k]
  unsigned short* Vt = VtS[wv];
  unsigned short* Pl = PlS[wv];

  const unsigned short* qb = Qh + (size_t)bh * 2048;
  const unsigned short* kb = Kh + (size_t)bh * 2048;
  const unsigned short* vg = Vh + (size_t)bh * 2048;

  bf16x8 vr[4];
#pragma unroll
  for (int i = 0; i < 4; ++i) vr[i] = ((const bf16x8*)(vg + lane * 32))[i];
  bf16x8 kf[4], qf[4];
#pragma unroll
  for (int nt = 0; nt < 4; ++nt)
    kf[nt] = *(const bf16x8*)(kb + (nt * 16 + lr) * 32 + lg * 8);
#pragma unroll
  for (int mt = 0; mt < 4; ++mt)
    qf[mt] = *(const bf16x8*)(qb + (mt * 16 + lr) * 32 + lg * 8);

  {
    __bf16* vt = (__bf16*)Vt;
#pragma unroll
    for (int d = 0; d < 8; ++d) {
      vt[(d)*72 + lane] = vr[0][d];
      vt[(d + 8) * 72 + lane] = vr[1][d];
      vt[(d + 16) * 72 + lane] = vr[2][d];
      vt[(d + 24) * 72 + lane] = vr[3][d];
    }
  }
  bf16x8 vfrag[2][2];
#pragma unroll
  for (int dt = 0; dt < 2; ++dt)
#pragma unroll
    for (int ki = 0; ki < 2; ++ki)
      vfrag[dt][ki] = *(const bf16x8*)(Vt + (dt * 16 + lr) * 72 + ki * 32 + lg * 8);

  const float* Mb = M + (size_t)((b & 63) * 16 + h) * 4096;

  f32x4 o[4][2];
#pragma unroll
  for (int i = 0; i < 4; ++i)
#pragma unroll
    for (int j = 0; j < 2; ++j) o[i][j] = f32x4{0.f, 0.f, 0.f, 0.f};
  float rinv[4][4];

#pragma unroll
  for (int mt = 0; mt < 4; ++mt) {
    float mv[4][4];
#pragma unroll
    for (int r = 0; r < 4; ++r)
#pragma unroll
      for (int nt = 0; nt < 4; ++nt)
        mv[r][nt] = Mb[(mt * 16 + lg * 4 + r) * 64 + nt * 16 + lr];

    f32x4 s[4];
#pragma unroll
    for (int nt = 0; nt < 4; ++nt) s[nt] = f32x4{0.f, 0.f, 0.f, 0.f};
#pragma unroll
    for (int nt = 0; nt < 4; ++nt)
      s[nt] = __builtin_amdgcn_mfma_f32_16x16x32_bf16(qf[mt], kf[nt], s[nt], 0, 0, 0);

#pragma unroll
    for (int r = 0; r < 4; ++r) {
      float v[4];
#pragma unroll
      for (int nt = 0; nt < 4; ++nt) v[nt] = s[nt][r] + mv[r][nt];
      float mx = fmaxf(fmaxf(v[0], v[1]), fmaxf(v[2], v[3]));
      mx = fmaxf(mx, __shfl_xor(mx, 1, 64));
      mx = fmaxf(mx, __shfl_xor(mx, 2, 64));
      mx = fmaxf(mx, __shfl_xor(mx, 4, 64));
      mx = fmaxf(mx, __shfl_xor(mx, 8, 64));
      float sum = 0.f;
#pragma unroll
      for (int nt = 0; nt < 4; ++nt) {
        v[nt] = __expf(v[nt] - mx);
        sum += v[nt];
      }
      sum += __shfl_xor(sum, 1, 64);
      sum += __shfl_xor(sum, 2, 64);
      sum += __shfl_xor(sum, 4, 64);
      sum += __shfl_xor(sum, 8, 64);
      rinv[mt][r] = __builtin_amdgcn_rcpf(sum);
#pragma unroll
      for (int nt = 0; nt < 4; ++nt)
        Pl[(lg * 4 + r) * 72 + nt * 16 + lr] = f2bf(v[nt]);
    }

    bf16x8 pa[2];
#pragma unroll
    for (int ki = 0; ki < 2; ++ki)
      pa[ki] = *(const bf16x8*)(Pl + lr * 72 + ki * 32 + lg * 8);
#pragma unroll
    for (int dt = 0; dt < 2; ++dt)
#pragma unroll
      for (int ki = 0; ki < 2; ++ki)
        o[mt][dt] = __builtin_amdgcn_mfma_f32_16x16x32_bf16(pa[ki], vfrag[dt][ki], o[mt][dt], 0, 0, 0);
  }

#pragma unroll
  for (int mt = 0; mt < 4; ++mt) {
#pragma unroll
    for (int r = 0; r < 4; ++r) {
      const int m = mt * 16 + lg * 4 + r;
      const float ri = rinv[mt][r];
#pragma unroll
      for (int dt = 0; dt < 2; ++dt) {
        const int d = dt * 16 + lr;
        attn_out[(size_t)(b * 64 + m) * 512 + h * 32 + d] = f2bf(o[mt][dt][r] * ri);
      }
    }
  }
}

// ---------------- launch ----------------
extern "C" void kernel_launch(void* const* d_in, const int* in_sizes, int n_in,
                              void* d_out, int out_size, void* d_ws, size_t ws_size,
                              hipStream_t stream) {
  const float* X = (const float*)d_in[0];
  const float* mask = (const float*)d_in[1];
  const float* qkv_w = (const float*)d_in[2];
  const float* qkv_b = (const float*)d_in[3];
  const float* proj_w = (const float*)d_in[4];
  const float* proj_b = (const float*)d_in[5];
  const float* bias_table = (const float*)d_in[6];
  float* out = (float*)d_out;
  char* ws = (char*)d_ws;

  // workspace layout (bytes)
  unsigned short* Xb      = (unsigned short*)(ws);                 // 134,217,728
  unsigned short* Qh      = (unsigned short*)(ws + 134217728ull);  // 134,217,728
  unsigned short* Kh      = (unsigned short*)(ws + 268435456ull);  // 134,217,728
  unsigned short* Vh      = (unsigned short*)(ws + 402653184ull);  // 134,217,728
  unsigned short* attnout = (unsigned short*)(ws + 536870912ull);  // 134,217,728
  unsigned short* qkv_wb  = (unsigned short*)(ws + 671088640ull);  // 1,572,864
  unsigned short* proj_wb = (unsigned short*)(ws + 672661504ull);  // 524,288
  float*          Mf      = (float*)(ws + 673185792ull);           // 16,777,216

  f32_to_bf16_vec4<<<2048, 256, 0, stream>>>(X, Xb, 67108864 / 4);
  f32_to_bf16_vec4<<<768, 256, 0, stream>>>(qkv_w, qkv_wb, 786432 / 4);
  f32_to_bf16_vec4<<<256, 256, 0, stream>>>(proj_w, proj_wb, 262144 / 4);
  build_bias_mask<<<16384, 256, 0, stream>>>(bias_table, mask, Mf);

  // QKV: M=131072, N=1536, K=512 -> head-blocked Q/K/V bf16; grid 512*6 = 3072
  gemm256<6, 2><<<3072, 512, 0, stream>>>(Xb, qkv_wb, qkv_b, (void*)Qh, (void*)Kh, (void*)Vh, 1536);

  // attention: 2 waves per block, wave per (b,h)
  attn_kernel<<<16384, 128, 0, stream>>>(Qh, Kh, Vh, Mf, attnout);

  // proj: M=131072, N=512, K=512 -> d_out f32; grid 512*2 = 1024
  gemm256<2, 0><<<1024, 512, 0, stream>>>(attnout, proj_wb, proj_b, (void*)out, nullptr, nullptr, 512);
}

// Round 5
// 579.887 us; speedup vs baseline: 1.7028x; 1.0278x over previous
//
#include <hip/hip_runtime.h>

typedef __bf16 bf16x8 __attribute__((ext_vector_type(8)));
typedef float f32x4 __attribute__((ext_vector_type(4)));

__device__ __forceinline__ unsigned short f2bf(float x) {
  union { float f; unsigned int u; } c; c.f = x;
  unsigned int r = c.u + 0x7FFFu + ((c.u >> 16) & 1u);
  return (unsigned short)(r >> 16);
}

// ---------------- convert f32 -> bf16 (vectorized) ----------------
__global__ __launch_bounds__(256) void f32_to_bf16_vec4(
    const float* __restrict__ in, unsigned short* __restrict__ out, int n4) {
  int i = blockIdx.x * blockDim.x + threadIdx.x;
  int stride = gridDim.x * blockDim.x;
  const float4* in4 = (const float4*)in;
  ushort4* out4 = (ushort4*)out;
  for (; i < n4; i += stride) {
    float4 f = in4[i];
    ushort4 u;
    u.x = f2bf(f.x); u.y = f2bf(f.y); u.z = f2bf(f.z); u.w = f2bf(f.w);
    out4[i] = u;
  }
}

// ---------------- fuse rel-pos bias + window mask: M[w][h][q][k] ----------------
__global__ __launch_bounds__(256) void build_bias_mask(
    const float* __restrict__ bias_table,  // [127][16]
    const float* __restrict__ mask,        // [64][64][64]
    float* __restrict__ M) {               // [64][16][64][64]
  const int idx = blockIdx.x * 256 + threadIdx.x;
  const int k = idx & 63, q = (idx >> 6) & 63, h = (idx >> 12) & 15, w = idx >> 16;
  M[idx] = bias_table[(q - k + 63) * 16 + h] + mask[(w * 64 + q) * 64 + k];
}

#define GLOAD_LDS16(gp, lp)                                                          \
  __builtin_amdgcn_global_load_lds(                                                  \
      (const __attribute__((address_space(1))) unsigned int*)(uintptr_t)(gp),        \
      (__attribute__((address_space(3))) unsigned int*)(uintptr_t)(lp), 16, 0, 0)

// ---------------- 256x256 GEMM, 16x16x32 MFMA, 4 phases/K-tile, reg-held fragments ----
// A: MxK bf16 row-major, B: NxK bf16 row-major. K=512. 512 threads = 8 waves (2M x 4N),
// wave tile 128x64. Per K-tile per wave: 24 ds_read_b128 (A 16KB + B 8KB, the minimum).
// B-frags held across the tile; A-frags held per 64-row half. Conflict-free round-3
// read pattern (chunk = kk*4+lg, row = lr). Uniform vmcnt(8) pipeline, depth ~2 tiles.
// EPI: 0 = f32 row-major out (C0, ldc); 2 = qkv-split head-blocked bf16 out (C0=Q,C1=K,C2=V)
template <int NBN, int EPI>
__global__ __launch_bounds__(512, 2) void gemm256(
    const unsigned short* __restrict__ A,
    const unsigned short* __restrict__ B,
    const float* __restrict__ bias,
    void* __restrict__ C0, void* __restrict__ C1, void* __restrict__ C2,
    int ldc) {
  constexpr int K = 512;
  constexpr int NT = K / 64;  // 8 K-tiles
  __shared__ __attribute__((aligned(128))) char lds[131072];

  const int t = threadIdx.x;
  const int lane = t & 63;
  const int wid = t >> 6;
  const int wr = wid >> 2, wc = wid & 3;
  const int lr = lane & 15, lg = lane >> 4;

  const int nwg = gridDim.x;
  const int cpx = nwg >> 3;
  const int wgid = (blockIdx.x & 7) * cpx + (blockIdx.x >> 3);
  const int bm = wgid / NBN, bn = wgid % NBN;
  const int m0 = bm * 256, n0 = bn * 256;

  const char* Ab = (const char*)(A + (size_t)m0 * K);
  const char* Bb = (const char*)(B + (size_t)n0 * K);

  const int r3 = t >> 3, ps = t & 7;

  // staging offsets: unit j, issue i (each issue = 64 rows, 512 thr x 16B)
  // UA_j = A rows [64j,64j+64) mod 128;  UB_j = B rows [32j,32j+32) mod 64.
  unsigned aoff[2][2], boff[2][2], adst[2][2], bdst[2][2];
#pragma unroll
  for (int j = 0; j < 2; ++j)
#pragma unroll
    for (int i = 0; i < 2; ++i) {
      const int rowA = i * 128 + j * 64 + r3;
      aoff[j][i] = (unsigned)((rowA * K + ((ps ^ (rowA & 7)) << 3)) * 2);
      adst[j][i] = (unsigned)(rowA * 128 + ps * 16);
      const int rowB = i * 128 + ((r3 >> 5) << 6) + j * 32 + (r3 & 31);
      boff[j][i] = (unsigned)((rowB * K + ((ps ^ (rowB & 7)) << 3)) * 2);
      bdst[j][i] = (unsigned)(65536 + rowB * 128 + ps * 16);
    }

#define STAGE_A(j, tt, buf)                                                   \
  do {                                                                        \
    GLOAD_LDS16(Ab + aoff[j][0] + (tt)*128, lds + (buf)*32768 + adst[j][0]);  \
    GLOAD_LDS16(Ab + aoff[j][1] + (tt)*128, lds + (buf)*32768 + adst[j][1]);  \
  } while (0)
#define STAGE_B(j, tt, buf)                                                   \
  do {                                                                        \
    GLOAD_LDS16(Bb + boff[j][0] + (tt)*128, lds + (buf)*32768 + bdst[j][0]);  \
    GLOAD_LDS16(Bb + boff[j][1] + (tt)*128, lds + (buf)*32768 + bdst[j][1]);  \
  } while (0)

  // fragment read bases (round-3 conflict-free pattern: row = lr, chunk = kk*4+lg)
  unsigned abase[2], bbase[2];
#pragma unroll
  for (int kk = 0; kk < 2; ++kk) {
    abase[kk] = (unsigned)((wr * 128 + lr) * 128 + (((kk * 4 + lg) ^ (lr & 7)) << 4));
    bbase[kk] = (unsigned)(65536 + (wc * 64 + lr) * 128 + (((kk * 4 + lg) ^ (lr & 7)) << 4));
  }

  f32x4 acc[8][4];
#pragma unroll
  for (int i = 0; i < 8; ++i)
#pragma unroll
    for (int j = 0; j < 4; ++j) acc[i][j] = f32x4{0.f, 0.f, 0.f, 0.f};

#define BAR_IN()                                         \
  __builtin_amdgcn_s_barrier();                          \
  asm volatile("s_waitcnt lgkmcnt(0)" ::: "memory");     \
  __builtin_amdgcn_sched_barrier(0);                     \
  __builtin_amdgcn_s_setprio(1)
#define MFMA16(QM, NTLO)                                                            \
  _Pragma("unroll") for (int mt = 0; mt < 4; ++mt)                                  \
    _Pragma("unroll") for (int nt = 0; nt < 2; ++nt)                                \
      _Pragma("unroll") for (int kk = 0; kk < 2; ++kk)                              \
        acc[(QM)*4 + mt][(NTLO) + nt] = __builtin_amdgcn_mfma_f32_16x16x32_bf16(    \
            af[mt][kk], bfr[(NTLO) + nt][kk], acc[(QM)*4 + mt][(NTLO) + nt], 0, 0, 0)

  // prologue: UA0(t0) UB0(t0) UB1(t0) UA1(t0) UA0(t1) UB0(t1)  (12 loads)
  STAGE_A(0, 0, 0); STAGE_B(0, 0, 0); STAGE_B(1, 0, 0); STAGE_A(1, 0, 0);
  STAGE_A(0, 1, 1); STAGE_B(0, 1, 1);
  asm volatile("s_waitcnt vmcnt(8)" ::: "memory");
  __builtin_amdgcn_s_barrier();

  // Deaths (tile tt, buf): UA0,UB0 after p0; UB1 after p1; UA1 after p2.
  // Stage: p0->UB1(tt+1,nb), p1->UA1(tt+1,nb), p2->UA0(tt+2,buf), p3->UB0(tt+2,buf).
#pragma unroll
  for (int tt = 0; tt < NT; ++tt) {
    const int buf = tt & 1;
    const int nb = buf ^ 1;
    bf16x8 af[4][2], bfr[4][2];
    // ---- p0: read B nt0-1 + A QM0; MFMA QM0 x nt0-1 ----
#pragma unroll
    for (int nt = 0; nt < 2; ++nt)
#pragma unroll
      for (int kk = 0; kk < 2; ++kk)
        bfr[nt][kk] = *(const bf16x8*)(lds + buf * 32768 + bbase[kk] + nt * 2048);
#pragma unroll
    for (int mt = 0; mt < 4; ++mt)
#pragma unroll
      for (int kk = 0; kk < 2; ++kk)
        af[mt][kk] = *(const bf16x8*)(lds + buf * 32768 + abase[kk] + mt * 2048);
    if (tt + 1 < NT) STAGE_B(1, tt + 1, nb);
    BAR_IN();
    MFMA16(0, 0);
    __builtin_amdgcn_s_setprio(0);
    if (tt == NT - 1) asm volatile("s_waitcnt vmcnt(2)" ::: "memory");
    else              asm volatile("s_waitcnt vmcnt(8)" ::: "memory");
    __builtin_amdgcn_s_barrier();
    // ---- p1: read B nt2-3; MFMA QM0 x nt2-3 ----
#pragma unroll
    for (int nt = 2; nt < 4; ++nt)
#pragma unroll
      for (int kk = 0; kk < 2; ++kk)
        bfr[nt][kk] = *(const bf16x8*)(lds + buf * 32768 + bbase[kk] + nt * 2048);
    if (tt + 1 < NT) STAGE_A(1, tt + 1, nb);
    BAR_IN();
    MFMA16(0, 2);
    __builtin_amdgcn_s_setprio(0);
    if (tt == NT - 1) asm volatile("s_waitcnt vmcnt(0)" ::: "memory");
    else              asm volatile("s_waitcnt vmcnt(8)" ::: "memory");
    __builtin_amdgcn_s_barrier();
    // ---- p2: read A QM1; MFMA QM1 x nt0-1 ----
#pragma unroll
    for (int mt = 0; mt < 4; ++mt)
#pragma unroll
      for (int kk = 0; kk < 2; ++kk)
        af[mt][kk] = *(const bf16x8*)(lds + buf * 32768 + abase[kk] + 8192 + mt * 2048);
    if (tt + 2 < NT) STAGE_A(0, tt + 2, buf);
    BAR_IN();
    MFMA16(1, 0);
    __builtin_amdgcn_s_setprio(0);
    if (tt < NT - 1) asm volatile("s_waitcnt vmcnt(8)" ::: "memory");
    __builtin_amdgcn_s_barrier();
    // ---- p3: no reads; MFMA QM1 x nt2-3 ----
    if (tt + 2 < NT) STAGE_B(0, tt + 2, buf);
    BAR_IN();
    MFMA16(1, 2);
    __builtin_amdgcn_s_setprio(0);
    if (tt < NT - 2)       asm volatile("s_waitcnt vmcnt(8)" ::: "memory");
    else if (tt == NT - 2) asm volatile("s_waitcnt vmcnt(4)" ::: "memory");
    __builtin_amdgcn_s_barrier();
  }
#undef MFMA16
#undef BAR_IN
#undef STAGE_A
#undef STAGE_B

  // epilogue: 16x16 C/D layout: col = lr, row = lg*4 + r
#pragma unroll
  for (int qm = 0; qm < 2; ++qm)
#pragma unroll
    for (int mt = 0; mt < 4; ++mt)
#pragma unroll
      for (int nt = 0; nt < 4; ++nt) {
        const int n = n0 + wc * 64 + nt * 16 + lr;
        const float bv = bias[n];
        const f32x4 a4 = acc[qm * 4 + mt][nt];
        if constexpr (EPI == 2) {
          const int part = n >> 9;
          unsigned short* dst = part == 0 ? (unsigned short*)C0
                                 : (part == 1 ? (unsigned short*)C1 : (unsigned short*)C2);
          const float sc = (part == 0) ? 0.17677669529663687f : 1.0f;
          const int hh = (n >> 5) & 15, dd = n & 31;
#pragma unroll
          for (int r = 0; r < 4; ++r) {
            const int m = m0 + wr * 128 + qm * 64 + mt * 16 + lg * 4 + r;
            dst[((size_t)((m >> 6) * 16 + hh) * 64 + (m & 63)) * 32 + dd] =
                f2bf((a4[r] + bv) * sc);
          }
        } else {
#pragma unroll
          for (int r = 0; r < 4; ++r) {
            const int m = m0 + wr * 128 + qm * 64 + mt * 16 + lg * 4 + r;
            ((float*)C0)[(size_t)m * ldc + n] = a4[r] + bv;
          }
        }
      }
}

// ---------------- fused window attention v3: head-blocked inputs, per-q-tile chain ----------------
// 128 threads = 2 waves, wave w handles (b,h) = blockIdx.x*2+w. No barriers (per-wave LDS).
__global__ __launch_bounds__(128) void attn_kernel(
    const unsigned short* __restrict__ Qh,  // [32768][64][32] bf16, pre-scaled
    const unsigned short* __restrict__ Kh,  // [32768][64][32]
    const unsigned short* __restrict__ Vh,  // [32768][64][32]
    const float* __restrict__ M,            // [64][16][64][64] fused bias+mask
    unsigned short* __restrict__ attn_out   // [131072][512] bf16, col = h*32+d
) {
  const int wv = threadIdx.x >> 6;
  const int bh = blockIdx.x * 2 + wv;
  const int b = bh >> 4, h = bh & 15;
  const int lane = threadIdx.x & 63;
  const int lr = lane & 15, lg = lane >> 4;

  __shared__ unsigned short VtS[2][32 * 72];  // V^T per wave: [d][k], stride 72
  __shared__ unsigned short PlS[2][16 * 72];  // P-slice per wave: [16 q][k]
  unsigned short* Vt = VtS[wv];
  unsigned short* Pl = PlS[wv];

  const unsigned short* qb = Qh + (size_t)bh * 2048;
  const unsigned short* kb = Kh + (size_t)bh * 2048;
  const unsigned short* vg = Vh + (size_t)bh * 2048;

  bf16x8 vr[4];
#pragma unroll
  for (int i = 0; i < 4; ++i) vr[i] = ((const bf16x8*)(vg + lane * 32))[i];
  bf16x8 kf[4], qf[4];
#pragma unroll
  for (int nt = 0; nt < 4; ++nt)
    kf[nt] = *(const bf16x8*)(kb + (nt * 16 + lr) * 32 + lg * 8);
#pragma unroll
  for (int mt = 0; mt < 4; ++mt)
    qf[mt] = *(const bf16x8*)(qb + (mt * 16 + lr) * 32 + lg * 8);

  {
    __bf16* vt = (__bf16*)Vt;
#pragma unroll
    for (int d = 0; d < 8; ++d) {
      vt[(d)*72 + lane] = vr[0][d];
      vt[(d + 8) * 72 + lane] = vr[1][d];
      vt[(d + 16) * 72 + lane] = vr[2][d];
      vt[(d + 24) * 72 + lane] = vr[3][d];
    }
  }
  bf16x8 vfrag[2][2];
#pragma unroll
  for (int dt = 0; dt < 2; ++dt)
#pragma unroll
    for (int ki = 0; ki < 2; ++ki)
      vfrag[dt][ki] = *(const bf16x8*)(Vt + (dt * 16 + lr) * 72 + ki * 32 + lg * 8);

  const float* Mb = M + (size_t)((b & 63) * 16 + h) * 4096;

  f32x4 o[4][2];
#pragma unroll
  for (int i = 0; i < 4; ++i)
#pragma unroll
    for (int j = 0; j < 2; ++j) o[i][j] = f32x4{0.f, 0.f, 0.f, 0.f};
  float rinv[4][4];

#pragma unroll
  for (int mt = 0; mt < 4; ++mt) {
    float mv[4][4];
#pragma unroll
    for (int r = 0; r < 4; ++r)
#pragma unroll
      for (int nt = 0; nt < 4; ++nt)
        mv[r][nt] = Mb[(mt * 16 + lg * 4 + r) * 64 + nt * 16 + lr];

    f32x4 s[4];
#pragma unroll
    for (int nt = 0; nt < 4; ++nt) s[nt] = f32x4{0.f, 0.f, 0.f, 0.f};
#pragma unroll
    for (int nt = 0; nt < 4; ++nt)
      s[nt] = __builtin_amdgcn_mfma_f32_16x16x32_bf16(qf[mt], kf[nt], s[nt], 0, 0, 0);

#pragma unroll
    for (int r = 0; r < 4; ++r) {
      float v[4];
#pragma unroll
      for (int nt = 0; nt < 4; ++nt) v[nt] = s[nt][r] + mv[r][nt];
      float mx = fmaxf(fmaxf(v[0], v[1]), fmaxf(v[2], v[3]));
      mx = fmaxf(mx, __shfl_xor(mx, 1, 64));
      mx = fmaxf(mx, __shfl_xor(mx, 2, 64));
      mx = fmaxf(mx, __shfl_xor(mx, 4, 64));
      mx = fmaxf(mx, __shfl_xor(mx, 8, 64));
      float sum = 0.f;
#pragma unroll
      for (int nt = 0; nt < 4; ++nt) {
        v[nt] = __expf(v[nt] - mx);
        sum += v[nt];
      }
      sum += __shfl_xor(sum, 1, 64);
      sum += __shfl_xor(sum, 2, 64);
      sum += __shfl_xor(sum, 4, 64);
      sum += __shfl_xor(sum, 8, 64);
      rinv[mt][r] = __builtin_amdgcn_rcpf(sum);
#pragma unroll
      for (int nt = 0; nt < 4; ++nt)
        Pl[(lg * 4 + r) * 72 + nt * 16 + lr] = f2bf(v[nt]);
    }

    bf16x8 pa[2];
#pragma unroll
    for (int ki = 0; ki < 2; ++ki)
      pa[ki] = *(const bf16x8*)(Pl + lr * 72 + ki * 32 + lg * 8);
#pragma unroll
    for (int dt = 0; dt < 2; ++dt)
#pragma unroll
      for (int ki = 0; ki < 2; ++ki)
        o[mt][dt] = __builtin_amdgcn_mfma_f32_16x16x32_bf16(pa[ki], vfrag[dt][ki], o[mt][dt], 0, 0, 0);
  }

#pragma unroll
  for (int mt = 0; mt < 4; ++mt) {
#pragma unroll
    for (int r = 0; r < 4; ++r) {
      const int m = mt * 16 + lg * 4 + r;
      const float ri = rinv[mt][r];
#pragma unroll
      for (int dt = 0; dt < 2; ++dt) {
        const int d = dt * 16 + lr;
        attn_out[(size_t)(b * 64 + m) * 512 + h * 32 + d] = f2bf(o[mt][dt][r] * ri);
      }
    }
  }
}

// ---------------- launch ----------------
extern "C" void kernel_launch(void* const* d_in, const int* in_sizes, int n_in,
                              void* d_out, int out_size, void* d_ws, size_t ws_size,
                              hipStream_t stream) {
  const float* X = (const float*)d_in[0];
  const float* mask = (const float*)d_in[1];
  const float* qkv_w = (const float*)d_in[2];
  const float* qkv_b = (const float*)d_in[3];
  const float* proj_w = (const float*)d_in[4];
  const float* proj_b = (const float*)d_in[5];
  const float* bias_table = (const float*)d_in[6];
  float* out = (float*)d_out;
  char* ws = (char*)d_ws;

  // workspace layout (bytes)
  unsigned short* Xb      = (unsigned short*)(ws);                 // 134,217,728
  unsigned short* Qh      = (unsigned short*)(ws + 134217728ull);  // 134,217,728
  unsigned short* Kh      = (unsigned short*)(ws + 268435456ull);  // 134,217,728
  unsigned short* Vh      = (unsigned short*)(ws + 402653184ull);  // 134,217,728
  unsigned short* attnout = (unsigned short*)(ws + 536870912ull);  // 134,217,728
  unsigned short* qkv_wb  = (unsigned short*)(ws + 671088640ull);  // 1,572,864
  unsigned short* proj_wb = (unsigned short*)(ws + 672661504ull);  // 524,288
  float*          Mf      = (float*)(ws + 673185792ull);           // 16,777,216

  f32_to_bf16_vec4<<<2048, 256, 0, stream>>>(X, Xb, 67108864 / 4);
  f32_to_bf16_vec4<<<768, 256, 0, stream>>>(qkv_w, qkv_wb, 786432 / 4);
  f32_to_bf16_vec4<<<256, 256, 0, stream>>>(proj_w, proj_wb, 262144 / 4);
  build_bias_mask<<<16384, 256, 0, stream>>>(bias_table, mask, Mf);

  // QKV: M=131072, N=1536, K=512 -> head-blocked Q/K/V bf16; grid 512*6 = 3072
  gemm256<6, 2><<<3072, 512, 0, stream>>>(Xb, qkv_wb, qkv_b, (void*)Qh, (void*)Kh, (void*)Vh, 1536);

  // attention: 2 waves per block, wave per (b,h)
  attn_kernel<<<16384, 128, 0, stream>>>(Qh, Kh, Vh, Mf, attnout);

  // proj: M=131072, N=512, K=512 -> d_out f32; grid 512*2 = 1024
  gemm256<2, 0><<<1024, 512, 0, stream>>>(attnout, proj_wb, proj_b, (void*)out, nullptr, nullptr, 512);
}